// Round 1
// baseline (2372.819 us; speedup 1.0000x reference)
//
#include <hip/hip_runtime.h>
#include <cstdint>

// Problem constants (match reference)
#define NB  8
#define C2  256
#define C3  512
#define NCH 128
#define NN2 4096   // H*W
#define NN3 4096   // T*H3*W3

using f4 = float4;

__device__ __forceinline__ void fma4(float* acc, float a, const f4 w) {
    acc[0] = fmaf(a, w.x, acc[0]);
    acc[1] = fmaf(a, w.y, acc[1]);
    acc[2] = fmaf(a, w.z, acc[2]);
    acc[3] = fmaf(a, w.w, acc[3]);
}

// ---------------------------------------------------------------------------
// Kernel 1: Q projection.  Q[b][n][c] = sum_k f2d[b][k][n]*Wq[c][k] + bq[c]
// Block tile: 64 n-rows x 128 c-cols, 256 threads (16 tx: c, 16 ty: n), 4x8/thread
// ---------------------------------------------------------------------------
__global__ __launch_bounds__(256) void proj_q(const float* __restrict__ f2d,
                                              const float* __restrict__ Wq,
                                              const float* __restrict__ bq,
                                              float* __restrict__ Q) {
    __shared__ __align__(16) float As[32 * 68];    // [kk][nn], pad 68 vs stride conflicts
    __shared__ __align__(16) float Ws[32 * 132];   // [kk][cc], pad 132
    const int tid = threadIdx.x;
    const int b  = blockIdx.x >> 6;
    const int n0 = (blockIdx.x & 63) << 6;
    const int tx = tid & 15, ty = tid >> 4;
    float acc[4][2][4];
#pragma unroll
    for (int i = 0; i < 4; i++)
#pragma unroll
        for (int v = 0; v < 2; v++)
#pragma unroll
            for (int u = 0; u < 4; u++) acc[i][v][u] = 0.f;
    const float* Ab = f2d + (size_t)b * C2 * NN2 + n0;
    for (int k0 = 0; k0 < C2; k0 += 32) {
#pragma unroll
        for (int i = 0; i < 2; i++) {               // A tile 32k x 64n
            int cidx = tid + 256 * i;
            int kk = cidx >> 4, noff = (cidx & 15) << 2;
            *(f4*)(As + kk * 68 + noff) = *(const f4*)(Ab + (size_t)(k0 + kk) * NN2 + noff);
        }
#pragma unroll
        for (int i = 0; i < 4; i++) {               // W tile transposed -> [kk][cc]
            int cidx = tid + 256 * i;
            int cc = cidx >> 3, koff = (cidx & 7) << 2;
            f4 w = *(const f4*)(Wq + cc * C2 + k0 + koff);
            Ws[(koff + 0) * 132 + cc] = w.x;
            Ws[(koff + 1) * 132 + cc] = w.y;
            Ws[(koff + 2) * 132 + cc] = w.z;
            Ws[(koff + 3) * 132 + cc] = w.w;
        }
        __syncthreads();
#pragma unroll 8
        for (int kk = 0; kk < 32; kk++) {
            f4 a4 = *(const f4*)(As + kk * 68 + 4 * ty);
            f4 w0 = *(const f4*)(Ws + kk * 132 + 4 * tx);
            f4 w1 = *(const f4*)(Ws + kk * 132 + 4 * tx + 64);
            float av[4] = {a4.x, a4.y, a4.z, a4.w};
#pragma unroll
            for (int i = 0; i < 4; i++) { fma4(acc[i][0], av[i], w0); fma4(acc[i][1], av[i], w1); }
        }
        __syncthreads();
    }
    f4 b0 = *(const f4*)(bq + 4 * tx);
    f4 b1 = *(const f4*)(bq + 4 * tx + 64);
#pragma unroll
    for (int i = 0; i < 4; i++) {
        float* row = Q + ((size_t)b * NN2 + n0 + 4 * ty + i) * NCH;
        f4 r0 = {acc[i][0][0] + b0.x, acc[i][0][1] + b0.y, acc[i][0][2] + b0.z, acc[i][0][3] + b0.w};
        f4 r1 = {acc[i][1][0] + b1.x, acc[i][1][1] + b1.y, acc[i][1][2] + b1.z, acc[i][1][3] + b1.w};
        *(f4*)(row + 4 * tx) = r0;
        *(f4*)(row + 4 * tx + 64) = r1;
    }
}

// ---------------------------------------------------------------------------
// Kernel 2: K and V projections fused (share the f3d tile).
// K[b][m][c], V[b][m][c]  (both stored n-major, c contiguous)
// ---------------------------------------------------------------------------
__global__ __launch_bounds__(256) void proj_kv(const float* __restrict__ f3d,
                                               const float* __restrict__ Wk,
                                               const float* __restrict__ bk,
                                               const float* __restrict__ Wv,
                                               const float* __restrict__ bv,
                                               float* __restrict__ K,
                                               float* __restrict__ V) {
    __shared__ __align__(16) float As[32 * 68];
    __shared__ __align__(16) float Wks[32 * 132];
    __shared__ __align__(16) float Wvs[32 * 132];
    const int tid = threadIdx.x;
    const int b  = blockIdx.x >> 6;
    const int n0 = (blockIdx.x & 63) << 6;
    const int tx = tid & 15, ty = tid >> 4;
    float acck[4][2][4], accv[4][2][4];
#pragma unroll
    for (int i = 0; i < 4; i++)
#pragma unroll
        for (int v = 0; v < 2; v++)
#pragma unroll
            for (int u = 0; u < 4; u++) { acck[i][v][u] = 0.f; accv[i][v][u] = 0.f; }
    const float* Ab = f3d + (size_t)b * C3 * NN3 + n0;
    for (int k0 = 0; k0 < C3; k0 += 32) {
#pragma unroll
        for (int i = 0; i < 2; i++) {
            int cidx = tid + 256 * i;
            int kk = cidx >> 4, noff = (cidx & 15) << 2;
            *(f4*)(As + kk * 68 + noff) = *(const f4*)(Ab + (size_t)(k0 + kk) * NN3 + noff);
        }
#pragma unroll
        for (int i = 0; i < 4; i++) {
            int cidx = tid + 256 * i;
            int cc = cidx >> 3, koff = (cidx & 7) << 2;
            f4 wkv = *(const f4*)(Wk + cc * C3 + k0 + koff);
            Wks[(koff + 0) * 132 + cc] = wkv.x;
            Wks[(koff + 1) * 132 + cc] = wkv.y;
            Wks[(koff + 2) * 132 + cc] = wkv.z;
            Wks[(koff + 3) * 132 + cc] = wkv.w;
            f4 wvv = *(const f4*)(Wv + cc * C3 + k0 + koff);
            Wvs[(koff + 0) * 132 + cc] = wvv.x;
            Wvs[(koff + 1) * 132 + cc] = wvv.y;
            Wvs[(koff + 2) * 132 + cc] = wvv.z;
            Wvs[(koff + 3) * 132 + cc] = wvv.w;
        }
        __syncthreads();
#pragma unroll 4
        for (int kk = 0; kk < 32; kk++) {
            f4 a4  = *(const f4*)(As + kk * 68 + 4 * ty);
            f4 k0v = *(const f4*)(Wks + kk * 132 + 4 * tx);
            f4 k1v = *(const f4*)(Wks + kk * 132 + 4 * tx + 64);
            f4 v0v = *(const f4*)(Wvs + kk * 132 + 4 * tx);
            f4 v1v = *(const f4*)(Wvs + kk * 132 + 4 * tx + 64);
            float av[4] = {a4.x, a4.y, a4.z, a4.w};
#pragma unroll
            for (int i = 0; i < 4; i++) {
                fma4(acck[i][0], av[i], k0v); fma4(acck[i][1], av[i], k1v);
                fma4(accv[i][0], av[i], v0v); fma4(accv[i][1], av[i], v1v);
            }
        }
        __syncthreads();
    }
    f4 bk0 = *(const f4*)(bk + 4 * tx);
    f4 bk1 = *(const f4*)(bk + 4 * tx + 64);
    f4 bv0 = *(const f4*)(bv + 4 * tx);
    f4 bv1 = *(const f4*)(bv + 4 * tx + 64);
#pragma unroll
    for (int i = 0; i < 4; i++) {
        size_t off = ((size_t)b * NN3 + n0 + 4 * ty + i) * NCH;
        f4 r0 = {acck[i][0][0] + bk0.x, acck[i][0][1] + bk0.y, acck[i][0][2] + bk0.z, acck[i][0][3] + bk0.w};
        f4 r1 = {acck[i][1][0] + bk1.x, acck[i][1][1] + bk1.y, acck[i][1][2] + bk1.z, acck[i][1][3] + bk1.w};
        *(f4*)(K + off + 4 * tx) = r0;
        *(f4*)(K + off + 4 * tx + 64) = r1;
        f4 s0 = {accv[i][0][0] + bv0.x, accv[i][0][1] + bv0.y, accv[i][0][2] + bv0.z, accv[i][0][3] + bv0.w};
        f4 s1 = {accv[i][1][0] + bv1.x, accv[i][1][1] + bv1.y, accv[i][1][2] + bv1.z, accv[i][1][3] + bv1.w};
        *(f4*)(V + off + 4 * tx) = s0;
        *(f4*)(V + off + 4 * tx + 64) = s1;
    }
}

// ---------------------------------------------------------------------------
// Kernel 3: flash attention (fp32), no score matrix materialization.
// Block: one batch b, 64 query rows. Tiles of 64 keys. 256 threads.
// S phase: 16x16 threads, 4n x 4m per thread. PV: same rows, c = 4tx+64v.
// K/V share one 32KB LDS buffer (K then V, barriered); XOR-swizzled layouts
// keep ds_read_b128 conflicts at <=2-way (free).
// ---------------------------------------------------------------------------
__global__ __launch_bounds__(256) void attn(const float* __restrict__ Q,
                                            const float* __restrict__ K,
                                            const float* __restrict__ V,
                                            float* __restrict__ AO) {
    __shared__ __align__(16) float Qs[64 * 128];
    __shared__ __align__(16) float KVs[64 * 128];
    const int tid = threadIdx.x;
    const int b  = blockIdx.x >> 6;
    const int n0 = (blockIdx.x & 63) << 6;
    const int tx = tid & 15, ty = tid >> 4;
    const int lane = tid & 63;
    const int src_base = lane & 48;        // 16-lane row-group base within wave
    const int qswz = (ty & 7) << 2;
    const int kswz = (tx & 7) << 2;

    const float* Qb = Q + ((size_t)b * NN2 + n0) * NCH;
#pragma unroll
    for (int i = 0; i < 8; i++) {
        int cidx = tid + 256 * i;
        int n = cidx >> 5, coff = (cidx & 31) << 2;
        *(f4*)(Qs + n * 128 + (coff ^ (((n >> 2) & 7) << 2))) =
            *(const f4*)(Qb + (size_t)n * NCH + coff);
    }
    float o[4][2][4];
#pragma unroll
    for (int i = 0; i < 4; i++)
#pragma unroll
        for (int v = 0; v < 2; v++)
#pragma unroll
            for (int u = 0; u < 4; u++) o[i][v][u] = 0.f;
    float m_run[4], l_run[4];
#pragma unroll
    for (int i = 0; i < 4; i++) { m_run[i] = -3.0e38f; l_run[i] = 0.f; }

    const float* Kb = K + (size_t)b * NN3 * NCH;
    const float* Vb = V + (size_t)b * NN3 * NCH;

    f4 kreg[8];
#pragma unroll
    for (int i = 0; i < 8; i++) {          // prefetch tile 0
        int cidx = tid + 256 * i;
        int m = cidx >> 5, coff = (cidx & 31) << 2;
        kreg[i] = *(const f4*)(Kb + (size_t)m * NCH + coff);
    }

    for (int m0 = 0; m0 < NN3; m0 += 64) {
        __syncthreads();                    // prev PV done reading KVs
#pragma unroll
        for (int i = 0; i < 8; i++) {       // KVs <- K tile (swizzled)
            int cidx = tid + 256 * i;
            int m = cidx >> 5, coff = (cidx & 31) << 2;
            *(f4*)(KVs + m * 128 + (coff ^ (((m >> 2) & 7) << 2))) = kreg[i];
        }
        __syncthreads();                    // K visible
        f4 vreg[8];
#pragma unroll
        for (int i = 0; i < 8; i++) {       // issue V loads early; land under S
            int cidx = tid + 256 * i;
            int m = cidx >> 5, coff = (cidx & 31) << 2;
            vreg[i] = *(const f4*)(Vb + (size_t)(m0 + m) * NCH + coff);
        }
        // ---- S = Q.K^T  (4x4 per thread) ----
        float s[4][4];
#pragma unroll
        for (int i = 0; i < 4; i++)
#pragma unroll
            for (int j = 0; j < 4; j++) s[i][j] = 0.f;
#pragma unroll 4
        for (int c0 = 0; c0 < 128; c0 += 4) {
            f4 q4[4], k4[4];
#pragma unroll
            for (int i = 0; i < 4; i++) q4[i] = *(const f4*)(Qs + (4 * ty + i) * 128 + (c0 ^ qswz));
#pragma unroll
            for (int j = 0; j < 4; j++) k4[j] = *(const f4*)(KVs + (4 * tx + j) * 128 + (c0 ^ kswz));
#pragma unroll
            for (int i = 0; i < 4; i++)
#pragma unroll
                for (int j = 0; j < 4; j++)
                    s[i][j] += q4[i].x * k4[j].x + q4[i].y * k4[j].y +
                               q4[i].z * k4[j].z + q4[i].w * k4[j].w;
        }
        // ---- online softmax (rows replicated over the 16-lane tx group) ----
        float p[4][4];
#pragma unroll
        for (int i = 0; i < 4; i++) {
            float tmax = fmaxf(fmaxf(s[i][0], s[i][1]), fmaxf(s[i][2], s[i][3]));
#pragma unroll
            for (int msk = 1; msk < 16; msk <<= 1) tmax = fmaxf(tmax, __shfl_xor(tmax, msk, 64));
            float newm = fmaxf(m_run[i], tmax);
            float psum = 0.f;
#pragma unroll
            for (int j = 0; j < 4; j++) { p[i][j] = __expf(s[i][j] - newm); psum += p[i][j]; }
#pragma unroll
            for (int msk = 1; msk < 16; msk <<= 1) psum += __shfl_xor(psum, msk, 64);
            float scale = __expf(m_run[i] - newm);
            l_run[i] = l_run[i] * scale + psum;
            m_run[i] = newm;
#pragma unroll
            for (int v = 0; v < 2; v++)
#pragma unroll
                for (int u = 0; u < 4; u++) o[i][v][u] *= scale;
        }
        __syncthreads();                    // S reads of KVs done
#pragma unroll
        for (int i = 0; i < 8; i++) {       // KVs <- V tile (swizzled)
            int cidx = tid + 256 * i;
            int m = cidx >> 5, coff = (cidx & 31) << 2;
            *(f4*)(KVs + m * 128 + (coff ^ (((m >> 2) & 7) << 2))) = vreg[i];
        }
        __syncthreads();                    // V visible
        int m0n = (m0 + 64 < NN3) ? (m0 + 64) : 0;
#pragma unroll
        for (int i = 0; i < 8; i++) {       // prefetch next K tile during PV
            int cidx = tid + 256 * i;
            int m = cidx >> 5, coff = (cidx & 31) << 2;
            kreg[i] = *(const f4*)(Kb + (size_t)(m0n + m) * NCH + coff);
        }
        // ---- O += P.V  (P rows broadcast via shfl from owning lanes) ----
        for (int mm0 = 0; mm0 < 64; mm0 += 4) {
            int src = src_base + (mm0 >> 2);
            int swz = ((mm0 >> 2) & 7) << 2;
            const float* vrow = KVs + mm0 * 128;
            int cA = (4 * tx) ^ swz;
#pragma unroll
            for (int jj = 0; jj < 4; jj++) {
                float pb[4];
#pragma unroll
                for (int i = 0; i < 4; i++) pb[i] = __shfl(p[i][jj], src, 64);
                f4 v0 = *(const f4*)(vrow + jj * 128 + cA);
                f4 v1 = *(const f4*)(vrow + jj * 128 + cA + 64);
#pragma unroll
                for (int i = 0; i < 4; i++) { fma4(o[i][0], pb[i], v0); fma4(o[i][1], pb[i], v1); }
            }
        }
    }
#pragma unroll
    for (int i = 0; i < 4; i++) {
        float inv = 1.0f / l_run[i];
        float* row = AO + ((size_t)b * NN2 + n0 + 4 * ty + i) * NCH;
        f4 r0 = {o[i][0][0] * inv, o[i][0][1] * inv, o[i][0][2] * inv, o[i][0][3] * inv};
        f4 r1 = {o[i][1][0] * inv, o[i][1][1] * inv, o[i][1][2] * inv, o[i][1][3] * inv};
        *(f4*)(row + 4 * tx) = r0;
        *(f4*)(row + 4 * tx + 64) = r1;
    }
}

// ---------------------------------------------------------------------------
// Kernel 4: X[b][co][n] = f2d[b][co][n] + bo[co] + sum_c Wo[co][c]*AO[b][n][c]
// Block tile: 64 co rows x 128 n cols (co-major output for the conv).
// ---------------------------------------------------------------------------
__global__ __launch_bounds__(256) void outproj(const float* __restrict__ AO,
                                               const float* __restrict__ Wo,
                                               const float* __restrict__ bo,
                                               const float* __restrict__ f2d,
                                               float* __restrict__ X) {
    __shared__ __align__(16) float Wt[32 * 68];    // [kk][co]
    __shared__ __align__(16) float At[32 * 132];   // [kk][nn]
    const int tid = threadIdx.x;
    const int b = blockIdx.x >> 7;
    const int r = blockIdx.x & 127;
    const int co0 = (r >> 5) << 6;
    const int n0  = (r & 31) << 7;
    const int tx = tid & 15, ty = tid >> 4;
    float acc[4][2][4];
#pragma unroll
    for (int i = 0; i < 4; i++)
#pragma unroll
        for (int v = 0; v < 2; v++)
#pragma unroll
            for (int u = 0; u < 4; u++) acc[i][v][u] = 0.f;
    for (int c0 = 0; c0 < NCH; c0 += 32) {
#pragma unroll
        for (int i = 0; i < 2; i++) {
            int cidx = tid + 256 * i;
            int cr = cidx >> 3, koff = (cidx & 7) << 2;
            f4 w = *(const f4*)(Wo + (co0 + cr) * NCH + c0 + koff);
            Wt[(koff + 0) * 68 + cr] = w.x;
            Wt[(koff + 1) * 68 + cr] = w.y;
            Wt[(koff + 2) * 68 + cr] = w.z;
            Wt[(koff + 3) * 68 + cr] = w.w;
        }
#pragma unroll
        for (int i = 0; i < 4; i++) {
            int cidx = tid + 256 * i;
            int nn = cidx >> 3, koff = (cidx & 7) << 2;
            f4 a = *(const f4*)(AO + ((size_t)b * NN2 + n0 + nn) * NCH + c0 + koff);
            At[(koff + 0) * 132 + nn] = a.x;
            At[(koff + 1) * 132 + nn] = a.y;
            At[(koff + 2) * 132 + nn] = a.z;
            At[(koff + 3) * 132 + nn] = a.w;
        }
        __syncthreads();
#pragma unroll 8
        for (int kk = 0; kk < 32; kk++) {
            f4 a4 = *(const f4*)(Wt + kk * 68 + 4 * ty);
            f4 x0 = *(const f4*)(At + kk * 132 + 4 * tx);
            f4 x1 = *(const f4*)(At + kk * 132 + 4 * tx + 64);
            float av[4] = {a4.x, a4.y, a4.z, a4.w};
#pragma unroll
            for (int i = 0; i < 4; i++) { fma4(acc[i][0], av[i], x0); fma4(acc[i][1], av[i], x1); }
        }
        __syncthreads();
    }
#pragma unroll
    for (int i = 0; i < 4; i++) {
        int co = co0 + 4 * ty + i;
        float bias = bo[co];
        const size_t rowb = ((size_t)b * C2 + co) * NN2 + n0;
#pragma unroll
        for (int v = 0; v < 2; v++) {
            size_t pidx = rowb + 4 * tx + 64 * v;
            f4 f = *(const f4*)(f2d + pidx);
            f4 out = {acc[i][v][0] + bias + f.x, acc[i][v][1] + bias + f.y,
                      acc[i][v][2] + bias + f.z, acc[i][v][3] + bias + f.w};
            *(f4*)(X + pidx) = out;
        }
    }
}

// ---------------------------------------------------------------------------
// Kernel 5: 3x3 SAME conv, 256->256 ch, + bps.
// Block: b x 64-co chunk x 16x16 spatial tile. Thread: 4 co x (4x4 pixels).
// 8 FMA per LDS float -> VALU-bound.
// ---------------------------------------------------------------------------
__global__ __launch_bounds__(256) void conv3x3(const float* __restrict__ X,
                                               const float* __restrict__ Wps,
                                               const float* __restrict__ bps,
                                               float* __restrict__ Y) {
    __shared__ float xt[8 * 324];                  // [ci][18][18] halo tile
    __shared__ __align__(16) float wt[8 * 64 * 12]; // [ci][co][12] (9 taps padded)
    const int tid = threadIdx.x;
    const int b = blockIdx.x >> 6;
    const int r = blockIdx.x & 63;
    const int co0 = (r >> 4) << 6;
    const int t4 = r & 15;
    const int y0 = (t4 >> 2) << 4;
    const int x0 = (t4 & 3) << 4;
    const int pixth = tid & 15;
    const int cog = tid >> 4;
    const int py = (pixth >> 2) << 2;
    const int px = (pixth & 3) << 2;
    const int cbase = co0 + cog * 4;
    float acc[4][16];
#pragma unroll
    for (int cc = 0; cc < 4; cc++)
#pragma unroll
        for (int pq = 0; pq < 16; pq++) acc[cc][pq] = 0.f;
    for (int ci0 = 0; ci0 < C2; ci0 += 8) {
        __syncthreads();                           // protect tiles from prev iter
        for (int idx = tid; idx < 8 * 324; idx += 256) {
            int ci = idx / 324;
            int rem = idx - ci * 324;
            int yy = rem / 18;
            int xx = rem - yy * 18;
            int gy = y0 - 1 + yy, gx = x0 - 1 + xx;
            float v = 0.f;
            if ((unsigned)gy < 64u && (unsigned)gx < 64u)
                v = X[(((size_t)b * C2 + ci0 + ci) * 64 + gy) * 64 + gx];
            xt[idx] = v;
        }
        for (int idx = tid; idx < 8 * 64 * 9; idx += 256) {
            int co = idx / 72;
            int rem = idx - co * 72;
            int ci = rem / 9;
            int k = rem - ci * 9;
            wt[(ci * 64 + co) * 12 + k] = Wps[(((size_t)(co0 + co)) * C2 + ci0 + ci) * 9 + k];
        }
        __syncthreads();
#pragma unroll
        for (int ci = 0; ci < 8; ci++) {
            float xv[6][6];
#pragma unroll
            for (int rr = 0; rr < 6; rr++)
#pragma unroll
                for (int ss = 0; ss < 6; ss++)
                    xv[rr][ss] = xt[ci * 324 + (py + rr) * 18 + (px + ss)];
#pragma unroll
            for (int cc = 0; cc < 4; cc++) {
                const float* wp = wt + ((ci * 64) + cog * 4 + cc) * 12;
                f4 wa = *(const f4*)(wp);
                f4 wb = *(const f4*)(wp + 4);
                f4 wc = *(const f4*)(wp + 8);
                float w9[9] = {wa.x, wa.y, wa.z, wa.w, wb.x, wb.y, wb.z, wb.w, wc.x};
#pragma unroll
                for (int oy = 0; oy < 4; oy++)
#pragma unroll
                    for (int ox = 0; ox < 4; ox++) {
                        float a = acc[cc][oy * 4 + ox];
#pragma unroll
                        for (int dy = 0; dy < 3; dy++)
#pragma unroll
                            for (int dx = 0; dx < 3; dx++)
                                a = fmaf(w9[dy * 3 + dx], xv[oy + dy][ox + dx], a);
                        acc[cc][oy * 4 + ox] = a;
                    }
            }
        }
    }
#pragma unroll
    for (int cc = 0; cc < 4; cc++) {
        float bias = bps[cbase + cc];
#pragma unroll
        for (int oy = 0; oy < 4; oy++) {
            size_t rowp = (((size_t)b * C2 + cbase + cc) * 64 + y0 + py + oy) * 64 + x0 + px;
            f4 out = {acc[cc][oy * 4 + 0] + bias, acc[cc][oy * 4 + 1] + bias,
                      acc[cc][oy * 4 + 2] + bias, acc[cc][oy * 4 + 3] + bias};
            *(f4*)(Y + rowp) = out;
        }
    }
}

// ---------------------------------------------------------------------------
// Workspace map (floats): Q[0,4M) K[4M,8M) V[8M,12M) AO[12M,16M)
// X (8.39M floats) reuses [0,8.39M) == Q+K exactly (dead after attn).
// Total ws requirement: 64 MiB.
// ---------------------------------------------------------------------------
extern "C" void kernel_launch(void* const* d_in, const int* in_sizes, int n_in,
                              void* d_out, int out_size, void* d_ws, size_t ws_size,
                              hipStream_t stream) {
    const float* f2d = (const float*)d_in[0];
    const float* f3d = (const float*)d_in[1];
    const float* Wq  = (const float*)d_in[2];
    const float* bq  = (const float*)d_in[3];
    const float* Wk  = (const float*)d_in[4];
    const float* bk  = (const float*)d_in[5];
    const float* Wv  = (const float*)d_in[6];
    const float* bv  = (const float*)d_in[7];
    const float* Wo  = (const float*)d_in[8];
    const float* bo  = (const float*)d_in[9];
    const float* Wps = (const float*)d_in[10];
    const float* bps = (const float*)d_in[11];
    float* Y  = (float*)d_out;
    float* ws = (float*)d_ws;
    float* Q  = ws;
    float* K  = ws + 4194304;
    float* V  = ws + 8388608;
    float* AO = ws + 12582912;
    float* X  = ws;   // overlaps Q,K — both dead once attn completes

    dim3 blk(256);
    proj_q  <<<dim3(512),  blk, 0, stream>>>(f2d, Wq, bq, Q);
    proj_kv <<<dim3(512),  blk, 0, stream>>>(f3d, Wk, bk, Wv, bv, K, V);
    attn    <<<dim3(512),  blk, 0, stream>>>(Q, K, V, AO);
    outproj <<<dim3(1024), blk, 0, stream>>>(AO, Wo, bo, f2d, X);
    conv3x3 <<<dim3(512),  blk, 0, stream>>>(X, Wps, bps, Y);
}

// Round 3
// 1113.858 us; speedup vs baseline: 2.1303x; 2.1303x over previous
//
#include <hip/hip_runtime.h>
#include <cstdint>

// Problem constants (match reference)
#define NB  8
#define C2  256
#define C3  512
#define NCH 128
#define NN2 4096   // H*W
#define NN3 4096   // T*H3*W3

using f4 = float4;
typedef float f32x16 __attribute__((ext_vector_type(16)));
typedef __bf16 bf16x8 __attribute__((ext_vector_type(8)));

union FragU {
    uint4    q;
    uint32_t u[4];
    bf16x8   v;
};

__device__ __forceinline__ void fma4(float* acc, float a, const f4 w) {
    acc[0] = fmaf(a, w.x, acc[0]);
    acc[1] = fmaf(a, w.y, acc[1]);
    acc[2] = fmaf(a, w.z, acc[2]);
    acc[3] = fmaf(a, w.w, acc[3]);
}

// exact RNE float->bf16 (finite inputs)
__device__ __forceinline__ unsigned short f2bf(float f) {
    uint32_t u = __float_as_uint(f);
    u += 0x7fffu + ((u >> 16) & 1u);
    return (unsigned short)(u >> 16);
}
__device__ __forceinline__ float bf2f(unsigned short h) {
    return __uint_as_float(((uint32_t)h) << 16);
}
// packed pair: low16 = bf16(lo), high16 = bf16(hi)  (compiler fuses to v_cvt_pk_bf16_f32)
__device__ __forceinline__ uint32_t pkbf(float lo, float hi) {
    union { __bf16 h[2]; uint32_t u; } t;
    t.h[0] = (__bf16)lo;
    t.h[1] = (__bf16)hi;
    return t.u;
}

// ---------------------------------------------------------------------------
// Kernel 1: Q projection -> bf16 Q[b][n][c]
// ---------------------------------------------------------------------------
__global__ __launch_bounds__(256) void proj_q(const float* __restrict__ f2d,
                                              const float* __restrict__ Wq,
                                              const float* __restrict__ bq,
                                              unsigned short* __restrict__ Q) {
    __shared__ __align__(16) float As[32 * 68];
    __shared__ __align__(16) float Ws[32 * 132];
    const int tid = threadIdx.x;
    const int b  = blockIdx.x >> 6;
    const int n0 = (blockIdx.x & 63) << 6;
    const int tx = tid & 15, ty = tid >> 4;
    float acc[4][2][4];
#pragma unroll
    for (int i = 0; i < 4; i++)
#pragma unroll
        for (int v = 0; v < 2; v++)
#pragma unroll
            for (int u = 0; u < 4; u++) acc[i][v][u] = 0.f;
    const float* Ab = f2d + (size_t)b * C2 * NN2 + n0;
    for (int k0 = 0; k0 < C2; k0 += 32) {
#pragma unroll
        for (int i = 0; i < 2; i++) {
            int cidx = tid + 256 * i;
            int kk = cidx >> 4, noff = (cidx & 15) << 2;
            *(f4*)(As + kk * 68 + noff) = *(const f4*)(Ab + (size_t)(k0 + kk) * NN2 + noff);
        }
#pragma unroll
        for (int i = 0; i < 4; i++) {
            int cidx = tid + 256 * i;
            int cc = cidx >> 3, koff = (cidx & 7) << 2;
            f4 w = *(const f4*)(Wq + cc * C2 + k0 + koff);
            Ws[(koff + 0) * 132 + cc] = w.x;
            Ws[(koff + 1) * 132 + cc] = w.y;
            Ws[(koff + 2) * 132 + cc] = w.z;
            Ws[(koff + 3) * 132 + cc] = w.w;
        }
        __syncthreads();
#pragma unroll 8
        for (int kk = 0; kk < 32; kk++) {
            f4 a4 = *(const f4*)(As + kk * 68 + 4 * ty);
            f4 w0 = *(const f4*)(Ws + kk * 132 + 4 * tx);
            f4 w1 = *(const f4*)(Ws + kk * 132 + 4 * tx + 64);
            float av[4] = {a4.x, a4.y, a4.z, a4.w};
#pragma unroll
            for (int i = 0; i < 4; i++) { fma4(acc[i][0], av[i], w0); fma4(acc[i][1], av[i], w1); }
        }
        __syncthreads();
    }
    f4 b0 = *(const f4*)(bq + 4 * tx);
    f4 b1 = *(const f4*)(bq + 4 * tx + 64);
    float ba[2][4] = {{b0.x, b0.y, b0.z, b0.w}, {b1.x, b1.y, b1.z, b1.w}};
#pragma unroll
    for (int i = 0; i < 4; i++) {
        unsigned short* row = Q + ((size_t)b * NN2 + n0 + 4 * ty + i) * NCH;
#pragma unroll
        for (int v = 0; v < 2; v++) {
            ushort4 r;
            r.x = f2bf(acc[i][v][0] + ba[v][0]);
            r.y = f2bf(acc[i][v][1] + ba[v][1]);
            r.z = f2bf(acc[i][v][2] + ba[v][2]);
            r.w = f2bf(acc[i][v][3] + ba[v][3]);
            *(ushort4*)(row + 4 * tx + 64 * v) = r;
        }
    }
}

// ---------------------------------------------------------------------------
// Kernel 2: K and V projections fused.
// K -> bf16 [b][m][c]; V -> bf16 TRANSPOSED Vt[b][c][m] (via LDS transpose)
// ---------------------------------------------------------------------------
__global__ __launch_bounds__(256) void proj_kv(const float* __restrict__ f3d,
                                               const float* __restrict__ Wk,
                                               const float* __restrict__ bk,
                                               const float* __restrict__ Wv,
                                               const float* __restrict__ bv,
                                               unsigned short* __restrict__ K,
                                               unsigned short* __restrict__ Vt) {
    __shared__ __align__(16) float smem[2176 + 4224 + 4224];
    float* As  = smem;
    float* Wks = smem + 2176;
    float* Wvs = smem + 2176 + 4224;
    const int tid = threadIdx.x;
    const int b  = blockIdx.x >> 6;
    const int n0 = (blockIdx.x & 63) << 6;
    const int tx = tid & 15, ty = tid >> 4;
    float acck[4][2][4], accv[4][2][4];
#pragma unroll
    for (int i = 0; i < 4; i++)
#pragma unroll
        for (int v = 0; v < 2; v++)
#pragma unroll
            for (int u = 0; u < 4; u++) { acck[i][v][u] = 0.f; accv[i][v][u] = 0.f; }
    const float* Ab = f3d + (size_t)b * C3 * NN3 + n0;
    for (int k0 = 0; k0 < C3; k0 += 32) {
#pragma unroll
        for (int i = 0; i < 2; i++) {
            int cidx = tid + 256 * i;
            int kk = cidx >> 4, noff = (cidx & 15) << 2;
            *(f4*)(As + kk * 68 + noff) = *(const f4*)(Ab + (size_t)(k0 + kk) * NN3 + noff);
        }
#pragma unroll
        for (int i = 0; i < 4; i++) {
            int cidx = tid + 256 * i;
            int cc = cidx >> 3, koff = (cidx & 7) << 2;
            f4 wkv = *(const f4*)(Wk + cc * C3 + k0 + koff);
            Wks[(koff + 0) * 132 + cc] = wkv.x;
            Wks[(koff + 1) * 132 + cc] = wkv.y;
            Wks[(koff + 2) * 132 + cc] = wkv.z;
            Wks[(koff + 3) * 132 + cc] = wkv.w;
            f4 wvv = *(const f4*)(Wv + cc * C3 + k0 + koff);
            Wvs[(koff + 0) * 132 + cc] = wvv.x;
            Wvs[(koff + 1) * 132 + cc] = wvv.y;
            Wvs[(koff + 2) * 132 + cc] = wvv.z;
            Wvs[(koff + 3) * 132 + cc] = wvv.w;
        }
        __syncthreads();
#pragma unroll 4
        for (int kk = 0; kk < 32; kk++) {
            f4 a4  = *(const f4*)(As + kk * 68 + 4 * ty);
            f4 k0v = *(const f4*)(Wks + kk * 132 + 4 * tx);
            f4 k1v = *(const f4*)(Wks + kk * 132 + 4 * tx + 64);
            f4 v0v = *(const f4*)(Wvs + kk * 132 + 4 * tx);
            f4 v1v = *(const f4*)(Wvs + kk * 132 + 4 * tx + 64);
            float av[4] = {a4.x, a4.y, a4.z, a4.w};
#pragma unroll
            for (int i = 0; i < 4; i++) {
                fma4(acck[i][0], av[i], k0v); fma4(acck[i][1], av[i], k1v);
                fma4(accv[i][0], av[i], v0v); fma4(accv[i][1], av[i], v1v);
            }
        }
        __syncthreads();
    }
    f4 bk0 = *(const f4*)(bk + 4 * tx);
    f4 bk1 = *(const f4*)(bk + 4 * tx + 64);
    f4 bv0 = *(const f4*)(bv + 4 * tx);
    f4 bv1 = *(const f4*)(bv + 4 * tx + 64);
    float bka[2][4] = {{bk0.x, bk0.y, bk0.z, bk0.w}, {bk1.x, bk1.y, bk1.z, bk1.w}};
    float bva[2][4] = {{bv0.x, bv0.y, bv0.z, bv0.w}, {bv1.x, bv1.y, bv1.z, bv1.w}};
    // K: bf16 row-major [m][c]
#pragma unroll
    for (int i = 0; i < 4; i++) {
        unsigned short* row = K + ((size_t)b * NN3 + n0 + 4 * ty + i) * NCH;
#pragma unroll
        for (int v = 0; v < 2; v++) {
            ushort4 r;
            r.x = f2bf(acck[i][v][0] + bka[v][0]);
            r.y = f2bf(acck[i][v][1] + bka[v][1]);
            r.z = f2bf(acck[i][v][2] + bka[v][2]);
            r.w = f2bf(acck[i][v][3] + bka[v][3]);
            *(ushort4*)(row + 4 * tx + 64 * v) = r;
        }
    }
    // V: transpose in LDS (smem dead now), then coalesced bf16 writes to Vt[b][c][m]
    unsigned short* vt = (unsigned short*)smem;   // [128 c][72 m-padded]
#pragma unroll
    for (int i = 0; i < 4; i++) {
        int ml = 4 * ty + i;
#pragma unroll
        for (int v = 0; v < 2; v++)
#pragma unroll
            for (int u = 0; u < 4; u++) {
                int c = 4 * tx + 64 * v + u;
                vt[c * 72 + ml] = f2bf(accv[i][v][u] + bva[v][u]);
            }
    }
    __syncthreads();
#pragma unroll
    for (int j = 0; j < 4; j++) {
        int idx = tid + 256 * j;          // 1024 chunks of 8 bf16
        int c = idx >> 3, gm = idx & 7;
        uint4 d = *(const uint4*)(vt + c * 72 + gm * 8);
        *(uint4*)(Vt + ((size_t)b * NCH + c) * NN3 + n0 + gm * 8) = d;
    }
}

// ---------------------------------------------------------------------------
// Kernel 3: flash attention, bf16 MFMA (32x32x16), fp32 accumulate.
// 128 threads = 2 waves; each wave owns 32 q-rows. KV tiles of 64.
// Swapped QK^T: S^T = mfma(K, Q) so softmax reduce = 1 shfl_xor(32) and
// P is lane-local; P->A-frag via packed bf16 pairs + 1 xor-32 shuffle.
// K tile [64][128] and Vt tile [128][64] in LDS, 16B-granule XOR swizzle
// (granule ^= row&7), double-buffered (64KB), async-split staging.
// ---------------------------------------------------------------------------
__global__ __launch_bounds__(128, 1) void attn(const unsigned short* __restrict__ Qg,
                                               const unsigned short* __restrict__ Kg,
                                               const unsigned short* __restrict__ Vtg,
                                               unsigned short* __restrict__ AO) {
    __shared__ __align__(16) unsigned short Ks[2][64 * 128];
    __shared__ __align__(16) unsigned short Vs[2][128 * 64];
    const int tid = threadIdx.x;
    const int b  = blockIdx.x >> 6;
    const int qc = blockIdx.x & 63;
    const int lane = tid & 63;
    const int wid = tid >> 6;
    const int i31 = lane & 31;
    const int h   = lane >> 5;
    const int q0w = qc * 64 + wid * 32;

    // Q fragments in registers: qf[dc] = Q[q0w + i31][16*dc + 8*h .. +7]
    uint4 qf[8];
    const unsigned short* Qrow = Qg + ((size_t)b * NN2 + q0w + i31) * NCH;
#pragma unroll
    for (int dc = 0; dc < 8; dc++) qf[dc] = *(const uint4*)(Qrow + dc * 16 + h * 8);

    f32x16 o[4];
#pragma unroll
    for (int cf = 0; cf < 4; cf++)
#pragma unroll
        for (int r = 0; r < 16; r++) o[cf][r] = 0.f;
    float m_run = -3.0e38f, l_run = 0.f;

    const unsigned short* Kb = Kg  + (size_t)b * NN3 * NCH;
    const unsigned short* Vb = Vtg + (size_t)b * NCH * NN3;

    uint4 kst[8], vst[8];
    // ---- prologue: stage tile 0 into buf 0 ----
#pragma unroll
    for (int j = 0; j < 8; j++) {
        int idx = tid + 128 * j;
        int key = idx >> 4, g = idx & 15;
        kst[j] = *(const uint4*)(Kb + (size_t)key * NCH + g * 8);
        int c = idx >> 3, gm = idx & 7;
        vst[j] = *(const uint4*)(Vb + (size_t)c * NN3 + gm * 8);
    }
#pragma unroll
    for (int j = 0; j < 8; j++) {
        int idx = tid + 128 * j;
        int key = idx >> 4, g = idx & 15;
        *(uint4*)(&Ks[0][key * 128 + ((g ^ (key & 7)) * 8)]) = kst[j];
        int c = idx >> 3, gm = idx & 7;
        *(uint4*)(&Vs[0][c * 64 + ((gm ^ (c & 7)) * 8)]) = vst[j];
    }
    __syncthreads();

    int buf = 0;
    for (int t = 0; t < 64; t++) {
        const bool more = (t + 1 < 64);
        const int m0n = more ? (t + 1) * 64 : 0;
        // ---- issue next-tile global loads early (latency hides under compute) ----
        if (more) {
#pragma unroll
            for (int j = 0; j < 8; j++) {
                int idx = tid + 128 * j;
                int key = idx >> 4, g = idx & 15;
                kst[j] = *(const uint4*)(Kb + (size_t)(m0n + key) * NCH + g * 8);
                int c = idx >> 3, gm = idx & 7;
                vst[j] = *(const uint4*)(Vb + (size_t)c * NN3 + m0n + gm * 8);
            }
        }
        // ---- QK^T: S^T = K_tile · Q^T ; sacc[kf] covers keys 32kf..32kf+31 ----
        f32x16 sacc[2];
#pragma unroll
        for (int kf = 0; kf < 2; kf++)
#pragma unroll
            for (int r = 0; r < 16; r++) sacc[kf][r] = 0.f;
#pragma unroll
        for (int dc = 0; dc < 8; dc++) {
            FragU bq; bq.q = qf[dc];
#pragma unroll
            for (int kf = 0; kf < 2; kf++) {
                FragU ak;
                ak.q = *(const uint4*)(&Ks[buf][(kf * 32 + i31) * 128 + (((2 * dc + h) ^ (i31 & 7)) * 8)]);
                sacc[kf] = __builtin_amdgcn_mfma_f32_32x32x16_bf16(ak.v, bq.v, sacc[kf], 0, 0, 0);
            }
        }
        // ---- online softmax; lane's q = i31; keys split across h halves ----
        float tmax = -3.0e38f;
#pragma unroll
        for (int kf = 0; kf < 2; kf++)
#pragma unroll
            for (int r = 0; r < 16; r++) tmax = fmaxf(tmax, sacc[kf][r]);
        tmax = fmaxf(tmax, __shfl_xor(tmax, 32, 64));
        if (__any(tmax > m_run)) {          // rescale path (exact skip otherwise)
            float newm = fmaxf(m_run, tmax);
            float scale = __expf(m_run - newm);
            m_run = newm;
            l_run *= scale;
#pragma unroll
            for (int reg = 0; reg < 16; reg++) {
                int qrow = (reg & 3) + 8 * (reg >> 2) + 4 * h;
                float sc = __shfl(scale, qrow, 64);
#pragma unroll
                for (int cf = 0; cf < 4; cf++) o[cf][reg] *= sc;
            }
        }
        float psum = 0.f;
#pragma unroll
        for (int kf = 0; kf < 2; kf++)
#pragma unroll
            for (int r = 0; r < 16; r++) {
                float e = __expf(sacc[kf][r] - m_run);
                sacc[kf][r] = e;
                psum += e;
            }
        psum += __shfl_xor(psum, 32, 64);
        l_run += psum;
        // ---- pack P to bf16 pairs: pk[kf][j] = (p[2j], p[2j+1]) ----
        uint32_t pk[2][8];
#pragma unroll
        for (int kf = 0; kf < 2; kf++)
#pragma unroll
            for (int j = 0; j < 8; j++) pk[kf][j] = pkbf(sacc[kf][2 * j], sacc[kf][2 * j + 1]);
        // ---- PV: O += P · V ----
#pragma unroll
        for (int kc = 0; kc < 4; kc++) {
            const int kf = kc >> 1, kcp = kc & 1;
            uint32_t own_lo  = pk[kf][4 * kcp + 0];
            uint32_t own_lo2 = pk[kf][4 * kcp + 1];
            uint32_t own_hi  = pk[kf][4 * kcp + 2];
            uint32_t own_hi2 = pk[kf][4 * kcp + 3];
            uint32_t send1 = h ? own_lo  : own_hi;
            uint32_t send2 = h ? own_lo2 : own_hi2;
            uint32_t recv1 = (uint32_t)__shfl_xor((int)send1, 32, 64);
            uint32_t recv2 = (uint32_t)__shfl_xor((int)send2, 32, 64);
            FragU pa;
            pa.u[0] = h ? recv1 : own_lo;
            pa.u[1] = h ? recv2 : own_lo2;
            pa.u[2] = h ? own_hi  : recv1;
            pa.u[3] = h ? own_hi2 : recv2;
#pragma unroll
            for (int cf = 0; cf < 4; cf++) {
                FragU vbf;
                vbf.q = *(const uint4*)(&Vs[buf][(cf * 32 + i31) * 64 + (((2 * kc + h) ^ (i31 & 7)) * 8)]);
                o[cf] = __builtin_amdgcn_mfma_f32_32x32x16_bf16(pa.v, vbf.v, o[cf], 0, 0, 0);
            }
        }
        // ---- write next tile into other buffer, swap ----
        if (more) {
#pragma unroll
            for (int j = 0; j < 8; j++) {
                int idx = tid + 128 * j;
                int key = idx >> 4, g = idx & 15;
                *(uint4*)(&Ks[buf ^ 1][key * 128 + ((g ^ (key & 7)) * 8)]) = kst[j];
                int c = idx >> 3, gm = idx & 7;
                *(uint4*)(&Vs[buf ^ 1][c * 64 + ((gm ^ (c & 7)) * 8)]) = vst[j];
            }
        }
        __syncthreads();
        buf ^= 1;
    }
    // ---- epilogue: normalize, write bf16 AO[b][n][c] ----
    float inv = 1.0f / l_run;
#pragma unroll
    for (int reg = 0; reg < 16; reg++) {
        int qrow = (reg & 3) + 8 * (reg >> 2) + 4 * h;
        float iv = __shfl(inv, qrow, 64);
        unsigned short* row = AO + ((size_t)b * NN2 + q0w + qrow) * NCH;
#pragma unroll
        for (int cf = 0; cf < 4; cf++) row[cf * 32 + i31] = f2bf(o[cf][reg] * iv);
    }
}

// ---------------------------------------------------------------------------
// Kernel 4: X[b][co][n] = f2d[b][co][n] + bo[co] + sum_c Wo[co][c]*AO[b][n][c]
// AO is now bf16.
// ---------------------------------------------------------------------------
__global__ __launch_bounds__(256) void outproj(const unsigned short* __restrict__ AO,
                                               const float* __restrict__ Wo,
                                               const float* __restrict__ bo,
                                               const float* __restrict__ f2d,
                                               float* __restrict__ X) {
    __shared__ __align__(16) float Wt[32 * 68];
    __shared__ __align__(16) float At[32 * 132];
    const int tid = threadIdx.x;
    const int b = blockIdx.x >> 7;
    const int r = blockIdx.x & 127;
    const int co0 = (r >> 5) << 6;
    const int n0  = (r & 31) << 7;
    const int tx = tid & 15, ty = tid >> 4;
    float acc[4][2][4];
#pragma unroll
    for (int i = 0; i < 4; i++)
#pragma unroll
        for (int v = 0; v < 2; v++)
#pragma unroll
            for (int u = 0; u < 4; u++) acc[i][v][u] = 0.f;
    for (int c0 = 0; c0 < NCH; c0 += 32) {
#pragma unroll
        for (int i = 0; i < 2; i++) {
            int cidx = tid + 256 * i;
            int cr = cidx >> 3, koff = (cidx & 7) << 2;
            f4 w = *(const f4*)(Wo + (co0 + cr) * NCH + c0 + koff);
            Wt[(koff + 0) * 68 + cr] = w.x;
            Wt[(koff + 1) * 68 + cr] = w.y;
            Wt[(koff + 2) * 68 + cr] = w.z;
            Wt[(koff + 3) * 68 + cr] = w.w;
        }
#pragma unroll
        for (int i = 0; i < 4; i++) {
            int cidx = tid + 256 * i;
            int nn = cidx >> 3, koff = (cidx & 7) << 2;
            ushort4 a4 = *(const ushort4*)(AO + ((size_t)b * NN2 + n0 + nn) * NCH + c0 + koff);
            At[(koff + 0) * 132 + nn] = bf2f(a4.x);
            At[(koff + 1) * 132 + nn] = bf2f(a4.y);
            At[(koff + 2) * 132 + nn] = bf2f(a4.z);
            At[(koff + 3) * 132 + nn] = bf2f(a4.w);
        }
        __syncthreads();
#pragma unroll 8
        for (int kk = 0; kk < 32; kk++) {
            f4 a4 = *(const f4*)(Wt + kk * 68 + 4 * ty);
            f4 x0 = *(const f4*)(At + kk * 132 + 4 * tx);
            f4 x1 = *(const f4*)(At + kk * 132 + 4 * tx + 64);
            float av[4] = {a4.x, a4.y, a4.z, a4.w};
#pragma unroll
            for (int i = 0; i < 4; i++) { fma4(acc[i][0], av[i], x0); fma4(acc[i][1], av[i], x1); }
        }
        __syncthreads();
    }
#pragma unroll
    for (int i = 0; i < 4; i++) {
        int co = co0 + 4 * ty + i;
        float bias = bo[co];
        const size_t rowb = ((size_t)b * C2 + co) * NN2 + n0;
#pragma unroll
        for (int v = 0; v < 2; v++) {
            size_t pidx = rowb + 4 * tx + 64 * v;
            f4 f = *(const f4*)(f2d + pidx);
            f4 out = {acc[i][v][0] + bias + f.x, acc[i][v][1] + bias + f.y,
                      acc[i][v][2] + bias + f.z, acc[i][v][3] + bias + f.w};
            *(f4*)(X + pidx) = out;
        }
    }
}

// ---------------------------------------------------------------------------
// Kernel 5: 3x3 SAME conv, 256->256 ch, + bps. (unchanged, fp32 vector)
// ---------------------------------------------------------------------------
__global__ __launch_bounds__(256) void conv3x3(const float* __restrict__ X,
                                               const float* __restrict__ Wps,
                                               const float* __restrict__ bps,
                                               float* __restrict__ Y) {
    __shared__ float xt[8 * 324];
    __shared__ __align__(16) float wt[8 * 64 * 12];
    const int tid = threadIdx.x;
    const int b = blockIdx.x >> 6;
    const int r = blockIdx.x & 63;
    const int co0 = (r >> 4) << 6;
    const int t4 = r & 15;
    const int y0 = (t4 >> 2) << 4;
    const int x0 = (t4 & 3) << 4;
    const int pixth = tid & 15;
    const int cog = tid >> 4;
    const int py = (pixth >> 2) << 2;
    const int px = (pixth & 3) << 2;
    const int cbase = co0 + cog * 4;
    float acc[4][16];
#pragma unroll
    for (int cc = 0; cc < 4; cc++)
#pragma unroll
        for (int pq = 0; pq < 16; pq++) acc[cc][pq] = 0.f;
    for (int ci0 = 0; ci0 < C2; ci0 += 8) {
        __syncthreads();
        for (int idx = tid; idx < 8 * 324; idx += 256) {
            int ci = idx / 324;
            int rem = idx - ci * 324;
            int yy = rem / 18;
            int xx = rem - yy * 18;
            int gy = y0 - 1 + yy, gx = x0 - 1 + xx;
            float v = 0.f;
            if ((unsigned)gy < 64u && (unsigned)gx < 64u)
                v = X[(((size_t)b * C2 + ci0 + ci) * 64 + gy) * 64 + gx];
            xt[idx] = v;
        }
        for (int idx = tid; idx < 8 * 64 * 9; idx += 256) {
            int co = idx / 72;
            int rem = idx - co * 72;
            int ci = rem / 9;
            int k = rem - ci * 9;
            wt[(ci * 64 + co) * 12 + k] = Wps[(((size_t)(co0 + co)) * C2 + ci0 + ci) * 9 + k];
        }
        __syncthreads();
#pragma unroll
        for (int ci = 0; ci < 8; ci++) {
            float xv[6][6];
#pragma unroll
            for (int rr = 0; rr < 6; rr++)
#pragma unroll
                for (int ss = 0; ss < 6; ss++)
                    xv[rr][ss] = xt[ci * 324 + (py + rr) * 18 + (px + ss)];
#pragma unroll
            for (int cc = 0; cc < 4; cc++) {
                const float* wp = wt + ((ci * 64) + cog * 4 + cc) * 12;
                f4 wa = *(const f4*)(wp);
                f4 wb = *(const f4*)(wp + 4);
                f4 wc = *(const f4*)(wp + 8);
                float w9[9] = {wa.x, wa.y, wa.z, wa.w, wb.x, wb.y, wb.z, wb.w, wc.x};
#pragma unroll
                for (int oy = 0; oy < 4; oy++)
#pragma unroll
                    for (int ox = 0; ox < 4; ox++) {
                        float a = acc[cc][oy * 4 + ox];
#pragma unroll
                        for (int dy = 0; dy < 3; dy++)
#pragma unroll
                            for (int dx = 0; dx < 3; dx++)
                                a = fmaf(w9[dy * 3 + dx], xv[oy + dy][ox + dx], a);
                        acc[cc][oy * 4 + ox] = a;
                    }
            }
        }
    }
#pragma unroll
    for (int cc = 0; cc < 4; cc++) {
        float bias = bps[cbase + cc];
#pragma unroll
        for (int oy = 0; oy < 4; oy++) {
            size_t rowp = (((size_t)b * C2 + cbase + cc) * 64 + y0 + py + oy) * 64 + x0 + px;
            f4 out = {acc[cc][oy * 4 + 0] + bias, acc[cc][oy * 4 + 1] + bias,
                      acc[cc][oy * 4 + 2] + bias, acc[cc][oy * 4 + 3] + bias};
            *(f4*)(Y + rowp) = out;
        }
    }
}

// ---------------------------------------------------------------------------
// Workspace (bytes): Q bf16 [0,8M) | K bf16 [8M,16M) | Vt bf16 [16M,24M)
//                    AO bf16 [24M,32M) | X f32 [32M,64M).  Total 64 MiB.
// ---------------------------------------------------------------------------
extern "C" void kernel_launch(void* const* d_in, const int* in_sizes, int n_in,
                              void* d_out, int out_size, void* d_ws, size_t ws_size,
                              hipStream_t stream) {
    const float* f2d = (const float*)d_in[0];
    const float* f3d = (const float*)d_in[1];
    const float* Wq  = (const float*)d_in[2];
    const float* bq  = (const float*)d_in[3];
    const float* Wk  = (const float*)d_in[4];
    const float* bk  = (const float*)d_in[5];
    const float* Wv  = (const float*)d_in[6];
    const float* bv  = (const float*)d_in[7];
    const float* Wo  = (const float*)d_in[8];
    const float* bo  = (const float*)d_in[9];
    const float* Wps = (const float*)d_in[10];
    const float* bps = (const float*)d_in[11];
    float* Y = (float*)d_out;

    unsigned short* Qb  = (unsigned short*)d_ws;
    unsigned short* Kb  = Qb + 4194304;
    unsigned short* Vtb = Kb + 4194304;
    unsigned short* AOb = Vtb + 4194304;
    float* X = (float*)((char*)d_ws + (size_t)32 * 1024 * 1024);

    dim3 blk(256);
    proj_q  <<<dim3(512),  blk, 0, stream>>>(f2d, Wq, bq, Qb);
    proj_kv <<<dim3(512),  blk, 0, stream>>>(f3d, Wk, bk, Wv, bv, Kb, Vtb);
    attn    <<<dim3(512),  dim3(128), 0, stream>>>(Qb, Kb, Vtb, AOb);
    outproj <<<dim3(1024), blk, 0, stream>>>(AOb, Wo, bo, f2d, X);
    conv3x3 <<<dim3(512),  blk, 0, stream>>>(X, Wps, bps, Y);
}

// Round 7
// 534.356 us; speedup vs baseline: 4.4405x; 2.0845x over previous
//
#include <hip/hip_runtime.h>
#include <cstdint>

// Problem constants (match reference)
#define NB  8
#define C2  256
#define C3  512
#define NCH 128
#define NN2 4096   // H*W
#define NN3 4096   // T*H3*W3

using f4 = float4;
typedef float f32x16 __attribute__((ext_vector_type(16)));
typedef __bf16 bf16x8 __attribute__((ext_vector_type(8)));

union FragU {
    uint4    q;
    uint32_t u[4];
    bf16x8   v;
};

__device__ __forceinline__ void fma4(float* acc, float a, const f4 w) {
    acc[0] = fmaf(a, w.x, acc[0]);
    acc[1] = fmaf(a, w.y, acc[1]);
    acc[2] = fmaf(a, w.z, acc[2]);
    acc[3] = fmaf(a, w.w, acc[3]);
}

// exact RNE float->bf16 (finite inputs)
__device__ __forceinline__ unsigned short f2bf(float f) {
    uint32_t u = __float_as_uint(f);
    u += 0x7fffu + ((u >> 16) & 1u);
    return (unsigned short)(u >> 16);
}
__device__ __forceinline__ float bf2f(unsigned short h) {
    return __uint_as_float(((uint32_t)h) << 16);
}
__device__ __forceinline__ uint32_t pkbf(float lo, float hi) {
    union { __bf16 h[2]; uint32_t u; } t;
    t.h[0] = (__bf16)lo;
    t.h[1] = (__bf16)hi;
    return t.u;
}

// ---------------------------------------------------------------------------
// Kernel 0: repack Wps [co][ci][3][3] f32 -> Wb [tap][co][ci] bf16
// ---------------------------------------------------------------------------
__global__ __launch_bounds__(256) void wprep(const float* __restrict__ Wps,
                                             unsigned short* __restrict__ Wb) {
    int idx = blockIdx.x * 256 + threadIdx.x;       // < 9*256*256 = 589824
    int t = idx >> 16;
    int r = idx & 65535;
    int co = r >> 8, ci = r & 255;
    Wb[idx] = f2bf(Wps[((size_t)(co * 256 + ci)) * 9 + t]);
}

// ---------------------------------------------------------------------------
// Kernel 1: Q projection -> bf16 Q[b][n][c]
// ---------------------------------------------------------------------------
__global__ __launch_bounds__(256) void proj_q(const float* __restrict__ f2d,
                                              const float* __restrict__ Wq,
                                              const float* __restrict__ bq,
                                              unsigned short* __restrict__ Q) {
    __shared__ __align__(16) float As[32 * 68];
    __shared__ __align__(16) float Ws[32 * 132];
    const int tid = threadIdx.x;
    const int b  = blockIdx.x >> 6;
    const int n0 = (blockIdx.x & 63) << 6;
    const int tx = tid & 15, ty = tid >> 4;
    float acc[4][2][4];
#pragma unroll
    for (int i = 0; i < 4; i++)
#pragma unroll
        for (int v = 0; v < 2; v++)
#pragma unroll
            for (int u = 0; u < 4; u++) acc[i][v][u] = 0.f;
    const float* Ab = f2d + (size_t)b * C2 * NN2 + n0;
    for (int k0 = 0; k0 < C2; k0 += 32) {
#pragma unroll
        for (int i = 0; i < 2; i++) {
            int cidx = tid + 256 * i;
            int kk = cidx >> 4, noff = (cidx & 15) << 2;
            *(f4*)(As + kk * 68 + noff) = *(const f4*)(Ab + (size_t)(k0 + kk) * NN2 + noff);
        }
#pragma unroll
        for (int i = 0; i < 4; i++) {
            int cidx = tid + 256 * i;
            int cc = cidx >> 3, koff = (cidx & 7) << 2;
            f4 w = *(const f4*)(Wq + cc * C2 + k0 + koff);
            Ws[(koff + 0) * 132 + cc] = w.x;
            Ws[(koff + 1) * 132 + cc] = w.y;
            Ws[(koff + 2) * 132 + cc] = w.z;
            Ws[(koff + 3) * 132 + cc] = w.w;
        }
        __syncthreads();
#pragma unroll 8
        for (int kk = 0; kk < 32; kk++) {
            f4 a4 = *(const f4*)(As + kk * 68 + 4 * ty);
            f4 w0 = *(const f4*)(Ws + kk * 132 + 4 * tx);
            f4 w1 = *(const f4*)(Ws + kk * 132 + 4 * tx + 64);
            float av[4] = {a4.x, a4.y, a4.z, a4.w};
#pragma unroll
            for (int i = 0; i < 4; i++) { fma4(acc[i][0], av[i], w0); fma4(acc[i][1], av[i], w1); }
        }
        __syncthreads();
    }
    f4 b0 = *(const f4*)(bq + 4 * tx);
    f4 b1 = *(const f4*)(bq + 4 * tx + 64);
    float ba[2][4] = {{b0.x, b0.y, b0.z, b0.w}, {b1.x, b1.y, b1.z, b1.w}};
#pragma unroll
    for (int i = 0; i < 4; i++) {
        unsigned short* row = Q + ((size_t)b * NN2 + n0 + 4 * ty + i) * NCH;
#pragma unroll
        for (int v = 0; v < 2; v++) {
            ushort4 r;
            r.x = f2bf(acc[i][v][0] + ba[v][0]);
            r.y = f2bf(acc[i][v][1] + ba[v][1]);
            r.z = f2bf(acc[i][v][2] + ba[v][2]);
            r.w = f2bf(acc[i][v][3] + ba[v][3]);
            *(ushort4*)(row + 4 * tx + 64 * v) = r;
        }
    }
}

// ---------------------------------------------------------------------------
// Kernel 2: K and V projections fused.
// K -> bf16 [b][m][c]; V -> bf16 TRANSPOSED Vt[b][c][m] (via LDS transpose)
// ---------------------------------------------------------------------------
__global__ __launch_bounds__(256) void proj_kv(const float* __restrict__ f3d,
                                               const float* __restrict__ Wk,
                                               const float* __restrict__ bk,
                                               const float* __restrict__ Wv,
                                               const float* __restrict__ bv,
                                               unsigned short* __restrict__ K,
                                               unsigned short* __restrict__ Vt) {
    __shared__ __align__(16) float smem[2176 + 4224 + 4224];
    float* As  = smem;
    float* Wks = smem + 2176;
    float* Wvs = smem + 2176 + 4224;
    const int tid = threadIdx.x;
    const int b  = blockIdx.x >> 6;
    const int n0 = (blockIdx.x & 63) << 6;
    const int tx = tid & 15, ty = tid >> 4;
    float acck[4][2][4], accv[4][2][4];
#pragma unroll
    for (int i = 0; i < 4; i++)
#pragma unroll
        for (int v = 0; v < 2; v++)
#pragma unroll
            for (int u = 0; u < 4; u++) { acck[i][v][u] = 0.f; accv[i][v][u] = 0.f; }
    const float* Ab = f3d + (size_t)b * C3 * NN3 + n0;
    for (int k0 = 0; k0 < C3; k0 += 32) {
#pragma unroll
        for (int i = 0; i < 2; i++) {
            int cidx = tid + 256 * i;
            int kk = cidx >> 4, noff = (cidx & 15) << 2;
            *(f4*)(As + kk * 68 + noff) = *(const f4*)(Ab + (size_t)(k0 + kk) * NN3 + noff);
        }
#pragma unroll
        for (int i = 0; i < 4; i++) {
            int cidx = tid + 256 * i;
            int cc = cidx >> 3, koff = (cidx & 7) << 2;
            f4 wkv = *(const f4*)(Wk + cc * C3 + k0 + koff);
            Wks[(koff + 0) * 132 + cc] = wkv.x;
            Wks[(koff + 1) * 132 + cc] = wkv.y;
            Wks[(koff + 2) * 132 + cc] = wkv.z;
            Wks[(koff + 3) * 132 + cc] = wkv.w;
            f4 wvv = *(const f4*)(Wv + cc * C3 + k0 + koff);
            Wvs[(koff + 0) * 132 + cc] = wvv.x;
            Wvs[(koff + 1) * 132 + cc] = wvv.y;
            Wvs[(koff + 2) * 132 + cc] = wvv.z;
            Wvs[(koff + 3) * 132 + cc] = wvv.w;
        }
        __syncthreads();
#pragma unroll 4
        for (int kk = 0; kk < 32; kk++) {
            f4 a4  = *(const f4*)(As + kk * 68 + 4 * ty);
            f4 k0v = *(const f4*)(Wks + kk * 132 + 4 * tx);
            f4 k1v = *(const f4*)(Wks + kk * 132 + 4 * tx + 64);
            f4 v0v = *(const f4*)(Wvs + kk * 132 + 4 * tx);
            f4 v1v = *(const f4*)(Wvs + kk * 132 + 4 * tx + 64);
            float av[4] = {a4.x, a4.y, a4.z, a4.w};
#pragma unroll
            for (int i = 0; i < 4; i++) {
                fma4(acck[i][0], av[i], k0v); fma4(acck[i][1], av[i], k1v);
                fma4(accv[i][0], av[i], v0v); fma4(accv[i][1], av[i], v1v);
            }
        }
        __syncthreads();
    }
    f4 bk0 = *(const f4*)(bk + 4 * tx);
    f4 bk1 = *(const f4*)(bk + 4 * tx + 64);
    f4 bv0 = *(const f4*)(bv + 4 * tx);
    f4 bv1 = *(const f4*)(bv + 4 * tx + 64);
    float bka[2][4] = {{bk0.x, bk0.y, bk0.z, bk0.w}, {bk1.x, bk1.y, bk1.z, bk1.w}};
    float bva[2][4] = {{bv0.x, bv0.y, bv0.z, bv0.w}, {bv1.x, bv1.y, bv1.z, bv1.w}};
#pragma unroll
    for (int i = 0; i < 4; i++) {
        unsigned short* row = K + ((size_t)b * NN3 + n0 + 4 * ty + i) * NCH;
#pragma unroll
        for (int v = 0; v < 2; v++) {
            ushort4 r;
            r.x = f2bf(acck[i][v][0] + bka[v][0]);
            r.y = f2bf(acck[i][v][1] + bka[v][1]);
            r.z = f2bf(acck[i][v][2] + bka[v][2]);
            r.w = f2bf(acck[i][v][3] + bka[v][3]);
            *(ushort4*)(row + 4 * tx + 64 * v) = r;
        }
    }
    unsigned short* vt = (unsigned short*)smem;   // [128 c][72 m-padded]
#pragma unroll
    for (int i = 0; i < 4; i++) {
        int ml = 4 * ty + i;
#pragma unroll
        for (int v = 0; v < 2; v++)
#pragma unroll
            for (int u = 0; u < 4; u++) {
                int c = 4 * tx + 64 * v + u;
                vt[c * 72 + ml] = f2bf(accv[i][v][u] + bva[v][u]);
            }
    }
    __syncthreads();
#pragma unroll
    for (int j = 0; j < 4; j++) {
        int idx = tid + 256 * j;
        int c = idx >> 3, gm = idx & 7;
        uint4 d = *(const uint4*)(vt + c * 72 + gm * 8);
        *(uint4*)(Vt + ((size_t)b * NCH + c) * NN3 + n0 + gm * 8) = d;
    }
}

// ---------------------------------------------------------------------------
// Kernel 3: flash attention, bf16 MFMA (unchanged from round 3)
// ---------------------------------------------------------------------------
__global__ __launch_bounds__(128, 1) void attn(const unsigned short* __restrict__ Qg,
                                               const unsigned short* __restrict__ Kg,
                                               const unsigned short* __restrict__ Vtg,
                                               unsigned short* __restrict__ AO) {
    __shared__ __align__(16) unsigned short Ks[2][64 * 128];
    __shared__ __align__(16) unsigned short Vs[2][128 * 64];
    const int tid = threadIdx.x;
    const int b  = blockIdx.x >> 6;
    const int qc = blockIdx.x & 63;
    const int lane = tid & 63;
    const int wid = tid >> 6;
    const int i31 = lane & 31;
    const int h   = lane >> 5;
    const int q0w = qc * 64 + wid * 32;

    uint4 qf[8];
    const unsigned short* Qrow = Qg + ((size_t)b * NN2 + q0w + i31) * NCH;
#pragma unroll
    for (int dc = 0; dc < 8; dc++) qf[dc] = *(const uint4*)(Qrow + dc * 16 + h * 8);

    f32x16 o[4];
#pragma unroll
    for (int cf = 0; cf < 4; cf++)
#pragma unroll
        for (int r = 0; r < 16; r++) o[cf][r] = 0.f;
    float m_run = -3.0e38f, l_run = 0.f;

    const unsigned short* Kb = Kg  + (size_t)b * NN3 * NCH;
    const unsigned short* Vb = Vtg + (size_t)b * NCH * NN3;

    uint4 kst[8], vst[8];
#pragma unroll
    for (int j = 0; j < 8; j++) {
        int idx = tid + 128 * j;
        int key = idx >> 4, g = idx & 15;
        kst[j] = *(const uint4*)(Kb + (size_t)key * NCH + g * 8);
        int c = idx >> 3, gm = idx & 7;
        vst[j] = *(const uint4*)(Vb + (size_t)c * NN3 + gm * 8);
    }
#pragma unroll
    for (int j = 0; j < 8; j++) {
        int idx = tid + 128 * j;
        int key = idx >> 4, g = idx & 15;
        *(uint4*)(&Ks[0][key * 128 + ((g ^ (key & 7)) * 8)]) = kst[j];
        int c = idx >> 3, gm = idx & 7;
        *(uint4*)(&Vs[0][c * 64 + ((gm ^ (c & 7)) * 8)]) = vst[j];
    }
    __syncthreads();

    int buf = 0;
    for (int t = 0; t < 64; t++) {
        const bool more = (t + 1 < 64);
        const int m0n = more ? (t + 1) * 64 : 0;
        if (more) {
#pragma unroll
            for (int j = 0; j < 8; j++) {
                int idx = tid + 128 * j;
                int key = idx >> 4, g = idx & 15;
                kst[j] = *(const uint4*)(Kb + (size_t)(m0n + key) * NCH + g * 8);
                int c = idx >> 3, gm = idx & 7;
                vst[j] = *(const uint4*)(Vb + (size_t)c * NN3 + m0n + gm * 8);
            }
        }
        f32x16 sacc[2];
#pragma unroll
        for (int kf = 0; kf < 2; kf++)
#pragma unroll
            for (int r = 0; r < 16; r++) sacc[kf][r] = 0.f;
#pragma unroll
        for (int dc = 0; dc < 8; dc++) {
            FragU bq; bq.q = qf[dc];
#pragma unroll
            for (int kf = 0; kf < 2; kf++) {
                FragU ak;
                ak.q = *(const uint4*)(&Ks[buf][(kf * 32 + i31) * 128 + (((2 * dc + h) ^ (i31 & 7)) * 8)]);
                sacc[kf] = __builtin_amdgcn_mfma_f32_32x32x16_bf16(ak.v, bq.v, sacc[kf], 0, 0, 0);
            }
        }
        float tmax = -3.0e38f;
#pragma unroll
        for (int kf = 0; kf < 2; kf++)
#pragma unroll
            for (int r = 0; r < 16; r++) tmax = fmaxf(tmax, sacc[kf][r]);
        tmax = fmaxf(tmax, __shfl_xor(tmax, 32, 64));
        if (__any(tmax > m_run)) {
            float newm = fmaxf(m_run, tmax);
            float scale = __expf(m_run - newm);
            m_run = newm;
            l_run *= scale;
#pragma unroll
            for (int reg = 0; reg < 16; reg++) {
                int qrow = (reg & 3) + 8 * (reg >> 2) + 4 * h;
                float sc = __shfl(scale, qrow, 64);
#pragma unroll
                for (int cf = 0; cf < 4; cf++) o[cf][reg] *= sc;
            }
        }
        float psum = 0.f;
#pragma unroll
        for (int kf = 0; kf < 2; kf++)
#pragma unroll
            for (int r = 0; r < 16; r++) {
                float e = __expf(sacc[kf][r] - m_run);
                sacc[kf][r] = e;
                psum += e;
            }
        psum += __shfl_xor(psum, 32, 64);
        l_run += psum;
        uint32_t pk[2][8];
#pragma unroll
        for (int kf = 0; kf < 2; kf++)
#pragma unroll
            for (int j = 0; j < 8; j++) pk[kf][j] = pkbf(sacc[kf][2 * j], sacc[kf][2 * j + 1]);
#pragma unroll
        for (int kc = 0; kc < 4; kc++) {
            const int kf = kc >> 1, kcp = kc & 1;
            uint32_t own_lo  = pk[kf][4 * kcp + 0];
            uint32_t own_lo2 = pk[kf][4 * kcp + 1];
            uint32_t own_hi  = pk[kf][4 * kcp + 2];
            uint32_t own_hi2 = pk[kf][4 * kcp + 3];
            uint32_t send1 = h ? own_lo  : own_hi;
            uint32_t send2 = h ? own_lo2 : own_hi2;
            uint32_t recv1 = (uint32_t)__shfl_xor((int)send1, 32, 64);
            uint32_t recv2 = (uint32_t)__shfl_xor((int)send2, 32, 64);
            FragU pa;
            pa.u[0] = h ? recv1 : own_lo;
            pa.u[1] = h ? recv2 : own_lo2;
            pa.u[2] = h ? own_hi  : recv1;
            pa.u[3] = h ? own_hi2 : recv2;
#pragma unroll
            for (int cf = 0; cf < 4; cf++) {
                FragU vbf;
                vbf.q = *(const uint4*)(&Vs[buf][(cf * 32 + i31) * 64 + (((2 * kc + h) ^ (i31 & 7)) * 8)]);
                o[cf] = __builtin_amdgcn_mfma_f32_32x32x16_bf16(pa.v, vbf.v, o[cf], 0, 0, 0);
            }
        }
        if (more) {
#pragma unroll
            for (int j = 0; j < 8; j++) {
                int idx = tid + 128 * j;
                int key = idx >> 4, g = idx & 15;
                *(uint4*)(&Ks[buf ^ 1][key * 128 + ((g ^ (key & 7)) * 8)]) = kst[j];
                int c = idx >> 3, gm = idx & 7;
                *(uint4*)(&Vs[buf ^ 1][c * 64 + ((gm ^ (c & 7)) * 8)]) = vst[j];
            }
        }
        __syncthreads();
        buf ^= 1;
    }
    float inv = 1.0f / l_run;
#pragma unroll
    for (int reg = 0; reg < 16; reg++) {
        int qrow = (reg & 3) + 8 * (reg >> 2) + 4 * h;
        float iv = __shfl(inv, qrow, 64);
        unsigned short* row = AO + ((size_t)b * NN2 + q0w + qrow) * NCH;
#pragma unroll
        for (int cf = 0; cf < 4; cf++) row[cf * 32 + i31] = f2bf(o[cf][reg] * iv);
    }
}

// ---------------------------------------------------------------------------
// Kernel 4: outproj -> X in bf16 NHWC: Xn[b][n][co] = f2d + bo + Wo·AO
// (LDS-transposed epilogue for contiguous NHWC 16B writes)
// ---------------------------------------------------------------------------
__global__ __launch_bounds__(256) void outproj(const unsigned short* __restrict__ AO,
                                               const float* __restrict__ Wo,
                                               const float* __restrict__ bo,
                                               const float* __restrict__ f2d,
                                               unsigned short* __restrict__ Xn) {
    __shared__ __align__(16) float smem[2176 + 4224];   // Wt | At ; reused as bf16 transpose buf
    float* Wt = smem;
    float* At = smem + 2176;
    const int tid = threadIdx.x;
    const int b = blockIdx.x >> 7;
    const int r = blockIdx.x & 127;
    const int co0 = (r >> 5) << 6;
    const int n0  = (r & 31) << 7;
    const int tx = tid & 15, ty = tid >> 4;
    float acc[4][2][4];
#pragma unroll
    for (int i = 0; i < 4; i++)
#pragma unroll
        for (int v = 0; v < 2; v++)
#pragma unroll
            for (int u = 0; u < 4; u++) acc[i][v][u] = 0.f;
    for (int c0 = 0; c0 < NCH; c0 += 32) {
#pragma unroll
        for (int i = 0; i < 2; i++) {
            int cidx = tid + 256 * i;
            int cr = cidx >> 3, koff = (cidx & 7) << 2;
            f4 w = *(const f4*)(Wo + (co0 + cr) * NCH + c0 + koff);
            Wt[(koff + 0) * 68 + cr] = w.x;
            Wt[(koff + 1) * 68 + cr] = w.y;
            Wt[(koff + 2) * 68 + cr] = w.z;
            Wt[(koff + 3) * 68 + cr] = w.w;
        }
#pragma unroll
        for (int i = 0; i < 4; i++) {
            int cidx = tid + 256 * i;
            int nn = cidx >> 3, koff = (cidx & 7) << 2;
            ushort4 a4 = *(const ushort4*)(AO + ((size_t)b * NN2 + n0 + nn) * NCH + c0 + koff);
            At[(koff + 0) * 132 + nn] = bf2f(a4.x);
            At[(koff + 1) * 132 + nn] = bf2f(a4.y);
            At[(koff + 2) * 132 + nn] = bf2f(a4.z);
            At[(koff + 3) * 132 + nn] = bf2f(a4.w);
        }
        __syncthreads();
#pragma unroll 8
        for (int kk = 0; kk < 32; kk++) {
            f4 a4 = *(const f4*)(Wt + kk * 68 + 4 * ty);
            f4 x0 = *(const f4*)(At + kk * 132 + 4 * tx);
            f4 x1 = *(const f4*)(At + kk * 132 + 4 * tx + 64);
            float av[4] = {a4.x, a4.y, a4.z, a4.w};
#pragma unroll
            for (int i = 0; i < 4; i++) { fma4(acc[i][0], av[i], x0); fma4(acc[i][1], av[i], x1); }
        }
        __syncthreads();
    }
    // transpose buffer: [128 n][72 co-padded] bf16  (18.4 KB, overlays Wt/At)
    unsigned short* tb = (unsigned short*)smem;
#pragma unroll
    for (int i = 0; i < 4; i++) {
        int co = co0 + 4 * ty + i;
        float bias = bo[co];
        const size_t rowb = ((size_t)b * C2 + co) * NN2 + n0;
#pragma unroll
        for (int v = 0; v < 2; v++) {
            size_t pidx = rowb + 4 * tx + 64 * v;
            f4 f = *(const f4*)(f2d + pidx);
            int nl = 4 * tx + 64 * v;
            tb[(nl + 0) * 72 + 4 * ty + i] = f2bf(acc[i][v][0] + bias + f.x);
            tb[(nl + 1) * 72 + 4 * ty + i] = f2bf(acc[i][v][1] + bias + f.y);
            tb[(nl + 2) * 72 + 4 * ty + i] = f2bf(acc[i][v][2] + bias + f.z);
            tb[(nl + 3) * 72 + 4 * ty + i] = f2bf(acc[i][v][3] + bias + f.w);
        }
    }
    __syncthreads();
    // BUGFIX (round 6): tile is 128 n x 64 co = 1024 16B-units -> k < 4, not 2.
#pragma unroll
    for (int k = 0; k < 4; k++) {
        int unit = tid + 256 * k;               // 1024 units of 16B
        int nl = unit >> 3, cc = unit & 7;
        uint4 d = *(const uint4*)(tb + nl * 72 + cc * 8);
        *(uint4*)(Xn + ((size_t)b * NN2 + n0 + nl) * C2 + co0 + cc * 8) = d;
    }
}

// ---------------------------------------------------------------------------
// Kernel 5: 3x3 conv via bf16 MFMA implicit GEMM.
// Block: 256 thr = 4 waves; tile 64 co x (32w x 8h) pixels; K = 256ci*9taps.
// X from bf16 NHWC (Xn), W from Wb[tap][co][ci] (direct global A-frags).
// LDS halo tile Xs[y 10][h 2][x 34][8 ci] -> wave-wide b128 reads hit 64
// distinct 16B slots (floor). Wave w: rows {2w,2w+1}, both co halves.
// ---------------------------------------------------------------------------
__global__ __launch_bounds__(256) void conv3x3(const unsigned short* __restrict__ Xn,
                                               const unsigned short* __restrict__ Wb,
                                               const float* __restrict__ bps,
                                               float* __restrict__ Y) {
    __shared__ __align__(16) unsigned short Xs[680 * 8];   // 10880 B
    const int tid = threadIdx.x;
    const int b  = blockIdx.x >> 6;
    const int r  = blockIdx.x & 63;
    const int ct = r >> 4;               // co tile (64 co)
    const int pt = r & 15;               // pixel tile
    const int px0 = (pt & 1) << 5;
    const int py0 = (pt >> 1) << 3;
    const int w    = tid >> 6;
    const int lane = tid & 63;
    const int i31  = lane & 31;
    const int h    = lane >> 5;
    const int co0  = ct << 6;

    f32x16 acc[2][2];
#pragma unroll
    for (int ch = 0; ch < 2; ch++)
#pragma unroll
        for (int pf = 0; pf < 2; pf++)
#pragma unroll
            for (int q = 0; q < 16; q++) acc[ch][pf][q] = 0.f;

    const unsigned short* Xb = Xn + (size_t)b * NN2 * C2;

    // stage unit u (< 680): pix = u>>1 -> (y = pix/34, x = pix%34), hh = u&1
    uint4 sreg[3];
    int su[3], sy[3], sx[3], sh[3];
#pragma unroll
    for (int k = 0; k < 3; k++) {
        int u = tid + 256 * k;
        su[k] = (u < 680);
        int pix = u >> 1;
        sy[k] = pix / 34;
        sx[k] = pix - sy[k] * 34;
        sh[k] = u & 1;
    }

    auto stage_load = [&](int ci0) {
#pragma unroll
        for (int k = 0; k < 3; k++) {
            uint4 z = {0, 0, 0, 0};
            if (su[k]) {
                int gy = py0 - 1 + sy[k];
                int gx = px0 - 1 + sx[k];
                if ((unsigned)gy < 64u && (unsigned)gx < 64u)
                    z = *(const uint4*)(Xb + ((size_t)(gy * 64 + gx)) * C2 + ci0 + 8 * sh[k]);
            }
            sreg[k] = z;
        }
    };
    auto stage_write = [&]() {
#pragma unroll
        for (int k = 0; k < 3; k++) {
            if (su[k]) {
                int slot = (sy[k] * 2 + sh[k]) * 34 + sx[k];
                *(uint4*)(&Xs[slot * 8]) = sreg[k];
            }
        }
    };

    stage_load(0);
    stage_write();
    __syncthreads();

    for (int c = 0; c < 16; c++) {
        const int ci0n = (c + 1) * 16;
        if (c + 1 < 16) stage_load(ci0n);
        const int ci0 = c * 16;
#pragma unroll
        for (int t = 0; t < 9; t++) {
            const int dy = t / 3, dx = t - dy * 3;
            FragU a0, a1;
            a0.q = *(const uint4*)(Wb + ((size_t)(t * 256 + co0 + i31)) * 256 + ci0 + 8 * h);
            a1.q = *(const uint4*)(Wb + ((size_t)(t * 256 + co0 + 32 + i31)) * 256 + ci0 + 8 * h);
#pragma unroll
            for (int pf = 0; pf < 2; pf++) {
                const int yl = 2 * w + pf;
                FragU bx;
                bx.q = *(const uint4*)(&Xs[(((yl + dy) * 2 + h) * 34 + i31 + dx) * 8]);
                acc[0][pf] = __builtin_amdgcn_mfma_f32_32x32x16_bf16(a0.v, bx.v, acc[0][pf], 0, 0, 0);
                acc[1][pf] = __builtin_amdgcn_mfma_f32_32x32x16_bf16(a1.v, bx.v, acc[1][pf], 0, 0, 0);
            }
        }
        __syncthreads();
        if (c + 1 < 16) stage_write();
        __syncthreads();
    }

    // epilogue: D col = i31 = x, row = (reg&3)+8*(reg>>2)+4*h = co_local
#pragma unroll
    for (int ch = 0; ch < 2; ch++)
#pragma unroll
        for (int pf = 0; pf < 2; pf++) {
            const int y = py0 + 2 * w + pf;
            const int x = px0 + i31;
#pragma unroll
            for (int q = 0; q < 16; q++) {
                int co = co0 + ch * 32 + (q & 3) + 8 * (q >> 2) + 4 * h;
                Y[(((size_t)b * C2 + co) * 64 + y) * 64 + x] = acc[ch][pf][q] + bps[co];
            }
        }
}

// ---------------------------------------------------------------------------
// Workspace (ushort elems): Q:0 | K:4194304 | Vt:8388608 | AO:12582912
//   | Xn(NHWC bf16): 16777216 (8.39M elem) | Wb: 25165824 (589824 elem)
// Total ~51.5 MiB.
// ---------------------------------------------------------------------------
extern "C" void kernel_launch(void* const* d_in, const int* in_sizes, int n_in,
                              void* d_out, int out_size, void* d_ws, size_t ws_size,
                              hipStream_t stream) {
    const float* f2d = (const float*)d_in[0];
    const float* f3d = (const float*)d_in[1];
    const float* Wq  = (const float*)d_in[2];
    const float* bq  = (const float*)d_in[3];
    const float* Wk  = (const float*)d_in[4];
    const float* bk  = (const float*)d_in[5];
    const float* Wv  = (const float*)d_in[6];
    const float* bv  = (const float*)d_in[7];
    const float* Wo  = (const float*)d_in[8];
    const float* bo  = (const float*)d_in[9];
    const float* Wps = (const float*)d_in[10];
    const float* bps = (const float*)d_in[11];
    float* Y = (float*)d_out;

    unsigned short* Qb  = (unsigned short*)d_ws;
    unsigned short* Kb  = Qb + 4194304;
    unsigned short* Vtb = Kb + 4194304;
    unsigned short* AOb = Vtb + 4194304;
    unsigned short* Xnb = AOb + 4194304;
    unsigned short* Wbb = Xnb + 8388608;

    dim3 blk(256);
    wprep   <<<dim3(2304), blk, 0, stream>>>(Wps, Wbb);
    proj_q  <<<dim3(512),  blk, 0, stream>>>(f2d, Wq, bq, Qb);
    proj_kv <<<dim3(512),  blk, 0, stream>>>(f3d, Wk, bk, Wv, bv, Kb, Vtb);
    attn    <<<dim3(512),  dim3(128), 0, stream>>>(Qb, Kb, Vtb, AOb);
    outproj <<<dim3(1024), blk, 0, stream>>>(AOb, Wo, bo, f2d, Xnb);
    conv3x3 <<<dim3(512),  blk, 0, stream>>>(Xnb, Wbb, bps, Y);
}